// Round 3
// baseline (661.344 us; speedup 1.0000x reference)
//
#include <hip/hip_runtime.h>

#define B_ 8
#define L_ 1024
#define S_ 1024
#define H_ 8
#define E_ 64
#define D_ 64

typedef __attribute__((ext_vector_type(8))) short bf16x8;
typedef __attribute__((ext_vector_type(4))) short bf16x4;
typedef __attribute__((ext_vector_type(4))) float f32x4;
typedef __attribute__((ext_vector_type(4))) ushort u16x4;

// round-to-nearest-even f32 -> bf16
__device__ __forceinline__ ushort f2b(float f) {
    unsigned u = __float_as_uint(f);
    return (ushort)((u + 0x7fffu + ((u >> 16) & 1u)) >> 16);
}
__device__ __forceinline__ float b2f(ushort b) {
    return __uint_as_float(((unsigned)b) << 16);
}

// K=16 bf16 MFMA: A/B = 4 bf16 per lane (m=lane&15, k=(lane>>4)*4+j),
// C/D = standard 16x16 (col=lane&15, row=(lane>>4)*4+r).
#if __has_builtin(__builtin_amdgcn_mfma_f32_16x16x16bf16_1k)
__device__ __forceinline__ f32x4 mfma16(bf16x4 a, bf16x4 b, f32x4 c) {
    return __builtin_amdgcn_mfma_f32_16x16x16bf16_1k(a, b, c, 0, 0, 0);
}
#elif __has_builtin(__builtin_amdgcn_mfma_f32_16x16x16_bf16)
__device__ __forceinline__ f32x4 mfma16(bf16x4 a, bf16x4 b, f32x4 c) {
    return __builtin_amdgcn_mfma_f32_16x16x16_bf16(a, b, c, 0, 0, 0);
}
#else
__device__ __forceinline__ f32x4 mfma16(bf16x4 a, bf16x4 b, f32x4 c) {
    f32x4 d;
    asm("v_mfma_f32_16x16x16_bf16 %0, %1, %2, %3" : "=v"(d) : "v"(a), "v"(b), "v"(c));
    return d;
}
#endif

// load 8 consecutive fp32 values and pack to a bf16x8 fragment
__device__ __forceinline__ bf16x8 load8_f2b(const float* p) {
    float4 a = *(const float4*)(p);
    float4 b = *(const float4*)(p + 4);
    bf16x8 r;
    r[0] = (short)f2b(a.x); r[1] = (short)f2b(a.y);
    r[2] = (short)f2b(a.z); r[3] = (short)f2b(a.w);
    r[4] = (short)f2b(b.x); r[5] = (short)f2b(b.y);
    r[6] = (short)f2b(b.z); r[7] = (short)f2b(b.w);
    return r;
}

// ---------------- V transpose + bf16 convert: VT[b,h,d,s] = bf16(V[b,s,h,d]) ----------------
__global__ __launch_bounds__(256) void vt_kernel(const float* __restrict__ V,
                                                 ushort* __restrict__ VT) {
    __shared__ ushort tile[64][72];  // pad 72: transposed reads spread banks
    int bh = blockIdx.x >> 4;   // b*H + h
    int st = blockIdx.x & 15;   // 64-wide s tile
    int t  = threadIdx.x;
    int b = bh >> 3, h = bh & 7;

    int s_loc = t >> 2;
    int dg = (t & 3) << 4;      // 16 d-elements per thread
    const float* src = V + (((size_t)(b * S_ + st * 64 + s_loc) * H_ + h) * D_ + dg);
#pragma unroll
    for (int v = 0; v < 4; ++v) {
        float4 f = *(const float4*)(src + v * 4);
        tile[s_loc][dg + v * 4 + 0] = f2b(f.x);
        tile[s_loc][dg + v * 4 + 1] = f2b(f.y);
        tile[s_loc][dg + v * 4 + 2] = f2b(f.z);
        tile[s_loc][dg + v * 4 + 3] = f2b(f.w);
    }
    __syncthreads();

    int d = t >> 2;
    int sg = (t & 3) << 4;
    ushort tmp[16];
#pragma unroll
    for (int i = 0; i < 16; ++i) tmp[i] = tile[sg + i][d];
    ushort* dst = VT + (((size_t)bh * D_ + d) * S_ + st * 64 + sg);
    *(uint4*)(dst)     = *(uint4*)&tmp[0];
    *(uint4*)(dst + 8) = *(uint4*)&tmp[8];
}

// ---------------- K fp32 -> bf16 (same layout): removes 64x-redundant per-block f2b ----------------
__global__ __launch_bounds__(256) void kb_kernel(const float* __restrict__ K,
                                                 ushort* __restrict__ KB) {
    size_t i = ((size_t)blockIdx.x * 256 + threadIdx.x) * 8;
    float4 a = *(const float4*)(K + i);
    float4 b = *(const float4*)(K + i + 4);
    ushort o[8];
    o[0] = f2b(a.x); o[1] = f2b(a.y); o[2] = f2b(a.z); o[3] = f2b(a.w);
    o[4] = f2b(b.x); o[5] = f2b(b.y); o[6] = f2b(b.z); o[7] = f2b(b.w);
    *(uint4*)(KB + i) = *(uint4*)o;
}

// ---------------- fused attention, single-pass ----------------
// Swapped QK^T (mfma(K,Q)) puts score(l=l0+lm, s=c0+r) in registers — which is
// exactly the A-fragment layout of the K=16 PV MFMA. So p~ never touches LDS:
// it is stashed in 32 VGPRs (full-unroll static indexing), PV accumulates
// per-wave partial O in registers, outA is emitted from the stash after the
// row-sum barrier. LDS = 17 KB (cross-wave O reduction only) vs 33 KB before.
template <int USE_WS>
__global__ __launch_bounds__(256, 5) void attn_kernel(
    const float* __restrict__ Q, const float* __restrict__ K,
    const float* __restrict__ A, const ushort* __restrict__ KB,
    const ushort* __restrict__ VT, const float* __restrict__ V,
    float* __restrict__ outV, float* __restrict__ outA) {
    __shared__ float red[4][16];               // per-wave row sums
    __shared__ float obuf[4][16][66];          // per-wave partial O (pad 66: no bank conflicts)

    int idx  = blockIdx.x;
    int lt   = 63 - (idx & 63);   // heavy (high-l) tiles first
    int bh   = idx >> 6;
    int b    = bh >> 3, h = bh & 7;
    int l0   = lt << 4;
    int t    = threadIdx.x;
    int wave = t >> 6, lane = t & 63;
    int quad = lane >> 4, lm = lane & 15;

    // --- Q fragments (B-operand of swapped QK^T: n=lm, k=quad*8+j) ---
    const size_t qbase = ((size_t)(b * L_ + l0 + lm) * H_ + h) * E_ + quad * 8;
    bf16x8 qf0 = load8_f2b(Q + qbase);
    bf16x8 qf1 = load8_f2b(Q + qbase + 32);

    const float scale = 0.125f;  // 1/sqrt(64)
    int nsb = lt + 1;            // 16-wide s-blocks needed (causal)
    int rg  = l0 + lm;           // this lane's global l-row
    const float* Arow = A + ((size_t)bh * L_ + l0 + lm) * S_ + quad * 4;
    const ushort* VTrow = VT + ((size_t)bh * D_ + lm) * S_;  // d-row lm (dd adds 16*S_)

    // --- main loop: scores -> exp -> stash(bf16) + fused PV, all in registers ---
    float psum = 0.f;
    u16x4 stash[16];              // statically indexed (full unroll)
    f32x4 oacc[4] = {{0.f,0.f,0.f,0.f},{0.f,0.f,0.f,0.f},{0.f,0.f,0.f,0.f},{0.f,0.f,0.f,0.f}};
#pragma unroll
    for (int i = 0; i < 16; ++i) {
        int sb = wave + i * 4;    // wave w owns s-blocks w, w+4, ...
        if (sb < nsb) {
            int s0 = sb << 4;
            int c0 = s0 + quad * 4;
            const size_t kbase = ((size_t)(b * S_ + s0 + lm) * H_ + h) * E_ + quad * 8;
            bf16x8 kf0, kf1;
            if (USE_WS) {
                kf0 = *(const bf16x8*)(KB + kbase);
                kf1 = *(const bf16x8*)(KB + kbase + 32);
            } else {
                kf0 = load8_f2b(K + kbase);
                kf1 = load8_f2b(K + kbase + 32);
            }
            float4 a4 = *(const float4*)(Arow + s0);
            f32x4 acc = {0.f, 0.f, 0.f, 0.f};
            acc = __builtin_amdgcn_mfma_f32_16x16x32_bf16(kf0, qf0, acc, 0, 0, 0);
            acc = __builtin_amdgcn_mfma_f32_16x16x32_bf16(kf1, qf1, acc, 0, 0, 0);
            u16x4 ps;
            bf16x4 pf;
#pragma unroll
            for (int r = 0; r < 4; ++r) {
                float av = (r == 0) ? a4.x : (r == 1) ? a4.y : (r == 2) ? a4.z : a4.w;
                float z = acc[r] * scale + av;
                float p = (c0 + r <= rg) ? __expf(z) : 0.f;  // mask (incl. diagonal block)
                psum += p;
                ps[r] = f2b(p);
                pf[r] = (short)ps[r];
            }
            stash[i] = ps;
            // PV: O[l=quad*4+r][d=dd*16+lm] += P[lm-row][c0+j] * V[c0+j][d]
#pragma unroll
            for (int dd = 0; dd < 4; ++dd) {
                bf16x4 vf;
                if (USE_WS) {
                    u16x4 vr = *(const u16x4*)(VTrow + (size_t)dd * 16 * S_ + c0);
                    vf[0] = (short)vr[0]; vf[1] = (short)vr[1];
                    vf[2] = (short)vr[2]; vf[3] = (short)vr[3];
                } else {
#pragma unroll
                    for (int j = 0; j < 4; ++j)
                        vf[j] = (short)f2b(V[((size_t)(b * S_ + c0 + j) * H_ + h) * D_ + dd * 16 + lm]);
                }
                oacc[dd] = mfma16(pf, vf, oacc[dd]);
            }
        }
    }

    // --- row-sum reduce across quads, publish per-wave sums + partial O ---
    psum += __shfl_xor(psum, 16);
    psum += __shfl_xor(psum, 32);
    if (quad == 0) red[wave][lm] = psum;
#pragma unroll
    for (int dd = 0; dd < 4; ++dd)
#pragma unroll
        for (int r = 0; r < 4; ++r)
            obuf[wave][quad * 4 + r][dd * 16 + lm] = oacc[dd][r];
    __syncthreads();

    // --- outA: emit from stash, scaled by inv row sum; zeros beyond diagonal ---
    float invA = 1.0f / (red[0][lm] + red[1][lm] + red[2][lm] + red[3][lm]);
    float* Aout = outA + ((size_t)bh * L_ + l0 + lm) * S_ + quad * 4;
#pragma unroll
    for (int i = 0; i < 16; ++i) {
        int sb = wave + i * 4;
        int s0 = sb << 4;
        float4 o;
        if (sb < nsb) {
            u16x4 ps = stash[i];
            o.x = b2f(ps[0]) * invA;
            o.y = b2f(ps[1]) * invA;
            o.z = b2f(ps[2]) * invA;
            o.w = b2f(ps[3]) * invA;
        } else {
            o = make_float4(0.f, 0.f, 0.f, 0.f);
        }
        *(float4*)(Aout + s0) = o;
    }

    // --- outV: cross-wave O reduction + normalize ---
#pragma unroll
    for (int i = 0; i < 4; ++i) {
        int slot = t + i * 256;
        int l = slot >> 6, d = slot & 63;
        float sum = obuf[0][l][d] + obuf[1][l][d] + obuf[2][l][d] + obuf[3][l][d];
        float inv = 1.0f / (red[0][l] + red[1][l] + red[2][l] + red[3][l]);
        outV[((size_t)(b * L_ + l0 + l) * H_ + h) * D_ + d] = sum * inv;
    }
}

extern "C" void kernel_launch(void* const* d_in, const int* in_sizes, int n_in,
                              void* d_out, int out_size, void* d_ws, size_t ws_size,
                              hipStream_t stream) {
    const float* Q = (const float*)d_in[0];
    const float* K = (const float*)d_in[1];
    const float* V = (const float*)d_in[2];
    // d_in[3] = attn_mask (bool): causal strict-upper-tri, synthesized in-kernel
    const float* A = (const float*)d_in[4];
    float* outV = (float*)d_out;                        // fp32 out: V (B,L,H,D)
    float* outA = outV + (size_t)B_ * L_ * H_ * D_;     // then A_new (B,H,L,S)

    size_t vt_elems = (size_t)B_ * H_ * D_ * S_;
    size_t kb_elems = (size_t)B_ * S_ * H_ * E_;
    size_t need = (vt_elems + kb_elems) * sizeof(ushort);
    ushort* VT = (ushort*)d_ws;
    ushort* KB = VT + vt_elems;

    if (ws_size >= need) {
        vt_kernel<<<B_ * H_ * (S_ / 64), 256, 0, stream>>>(V, VT);
        kb_kernel<<<(int)(kb_elems / (256 * 8)), 256, 0, stream>>>(K, KB);
        attn_kernel<1><<<B_ * H_ * (L_ / 16), 256, 0, stream>>>(Q, K, A, KB, VT, V, outV, outA);
    } else {
        attn_kernel<0><<<B_ * H_ * (L_ / 16), 256, 0, stream>>>(Q, K, A, KB, VT, V, outV, outA);
    }
}

// Round 4
// 622.124 us; speedup vs baseline: 1.0630x; 1.0630x over previous
//
#include <hip/hip_runtime.h>

#define B_ 8
#define L_ 1024
#define S_ 1024
#define H_ 8
#define E_ 64
#define D_ 64

typedef __attribute__((ext_vector_type(8))) short bf16x8;
typedef __attribute__((ext_vector_type(4))) short bf16x4;
typedef __attribute__((ext_vector_type(4))) float f32x4;
typedef __attribute__((ext_vector_type(4))) ushort u16x4;

// round-to-nearest-even f32 -> bf16
__device__ __forceinline__ ushort f2b(float f) {
    unsigned u = __float_as_uint(f);
    return (ushort)((u + 0x7fffu + ((u >> 16) & 1u)) >> 16);
}
__device__ __forceinline__ float b2f(ushort b) {
    return __uint_as_float(((unsigned)b) << 16);
}

// K=16 bf16 MFMA: A/B = 4 bf16 per lane (m=lane&15, k=(lane>>4)*4+j),
// C/D = standard 16x16 (col=lane&15, row=(lane>>4)*4+r).
#if __has_builtin(__builtin_amdgcn_mfma_f32_16x16x16bf16_1k)
__device__ __forceinline__ f32x4 mfma16(bf16x4 a, bf16x4 b, f32x4 c) {
    return __builtin_amdgcn_mfma_f32_16x16x16bf16_1k(a, b, c, 0, 0, 0);
}
#elif __has_builtin(__builtin_amdgcn_mfma_f32_16x16x16_bf16)
__device__ __forceinline__ f32x4 mfma16(bf16x4 a, bf16x4 b, f32x4 c) {
    return __builtin_amdgcn_mfma_f32_16x16x16_bf16(a, b, c, 0, 0, 0);
}
#else
__device__ __forceinline__ f32x4 mfma16(bf16x4 a, bf16x4 b, f32x4 c) {
    f32x4 d;
    asm("v_mfma_f32_16x16x16_bf16 %0, %1, %2, %3" : "=v"(d) : "v"(a), "v"(b), "v"(c));
    return d;
}
#endif

// load 8 consecutive fp32 values and pack to a bf16x8 fragment
__device__ __forceinline__ bf16x8 load8_f2b(const float* p) {
    float4 a = *(const float4*)(p);
    float4 b = *(const float4*)(p + 4);
    bf16x8 r;
    r[0] = (short)f2b(a.x); r[1] = (short)f2b(a.y);
    r[2] = (short)f2b(a.z); r[3] = (short)f2b(a.w);
    r[4] = (short)f2b(b.x); r[5] = (short)f2b(b.y);
    r[6] = (short)f2b(b.z); r[7] = (short)f2b(b.w);
    return r;
}

// ---------------- V transpose + bf16 convert: VT[b,h,d,s] = bf16(V[b,s,h,d]) ----------------
__global__ __launch_bounds__(256) void vt_kernel(const float* __restrict__ V,
                                                 ushort* __restrict__ VT) {
    __shared__ ushort tile[64][72];  // pad 72: transposed reads spread banks
    int bh = blockIdx.x >> 4;   // b*H + h
    int st = blockIdx.x & 15;   // 64-wide s tile
    int t  = threadIdx.x;
    int b = bh >> 3, h = bh & 7;

    int s_loc = t >> 2;
    int dg = (t & 3) << 4;      // 16 d-elements per thread
    const float* src = V + (((size_t)(b * S_ + st * 64 + s_loc) * H_ + h) * D_ + dg);
#pragma unroll
    for (int v = 0; v < 4; ++v) {
        float4 f = *(const float4*)(src + v * 4);
        tile[s_loc][dg + v * 4 + 0] = f2b(f.x);
        tile[s_loc][dg + v * 4 + 1] = f2b(f.y);
        tile[s_loc][dg + v * 4 + 2] = f2b(f.z);
        tile[s_loc][dg + v * 4 + 3] = f2b(f.w);
    }
    __syncthreads();

    int d = t >> 2;
    int sg = (t & 3) << 4;
    ushort tmp[16];
#pragma unroll
    for (int i = 0; i < 16; ++i) tmp[i] = tile[sg + i][d];
    ushort* dst = VT + (((size_t)bh * D_ + d) * S_ + st * 64 + sg);
    *(uint4*)(dst)     = *(uint4*)&tmp[0];
    *(uint4*)(dst + 8) = *(uint4*)&tmp[8];
}

// ---------------- K fp32 -> bf16 (same layout): removes 64x-redundant per-block f2b ----------------
__global__ __launch_bounds__(256) void kb_kernel(const float* __restrict__ K,
                                                 ushort* __restrict__ KB) {
    size_t i = ((size_t)blockIdx.x * 256 + threadIdx.x) * 8;
    float4 a = *(const float4*)(K + i);
    float4 b = *(const float4*)(K + i + 4);
    ushort o[8];
    o[0] = f2b(a.x); o[1] = f2b(a.y); o[2] = f2b(a.z); o[3] = f2b(a.w);
    o[4] = f2b(b.x); o[5] = f2b(b.y); o[6] = f2b(b.z); o[7] = f2b(b.w);
    *(uint4*)(KB + i) = *(uint4*)o;
}

// per-iteration operand bundle (kept in registers; depth-2 pipeline)
struct Frag {
    bf16x8 kf0, kf1;   // K fragments
    float4 a4;         // A bias (4 cols of this lane's row)
    u16x4  vr0, vr1, vr2, vr3;  // V fragments for 4 d-blocks
};

// ---------------- fused attention, single-pass + reg-PV + chunked-LDS outA ----------------
// Swapped QK^T (mfma(K,Q)): lane (quad,lm) holds score(l=l0+lm, s=s0+quad*4+r),
// which IS the A-fragment layout of the K=16 PV MFMA -> PV runs from registers.
// outA is emitted COALESCED (1KB/wave-instr) via a 4-chunk LDS transpose that
// reuses obuf's space (round-3's scattered 64B stores caused 1.37x HBM
// amplification). Main loop is software-pipelined depth-2 (prefetch K/A/V).
template <int USE_WS>
__global__ __launch_bounds__(256, 4) void attn_kernel(
    const float* __restrict__ Q, const float* __restrict__ K,
    const float* __restrict__ A, const ushort* __restrict__ KB,
    const ushort* __restrict__ VT, const float* __restrict__ V,
    float* __restrict__ outV, float* __restrict__ outA) {
    __shared__ float red[4][16];               // per-wave row sums
    __shared__ __align__(16) float obuf[4][16][66];  // partial O; later reused as outA stage

    int idx  = blockIdx.x;
    int lt   = 63 - (idx & 63);   // heavy (high-l) tiles first
    int bh   = idx >> 6;
    int b    = bh >> 3, h = bh & 7;
    int l0   = lt << 4;
    int t    = threadIdx.x;
    int wave = t >> 6, lane = t & 63;
    int quad = lane >> 4, lm = lane & 15;

    // --- Q fragments (B-operand of swapped QK^T: n=lm, k=quad*8+j) ---
    const size_t qbase = ((size_t)(b * L_ + l0 + lm) * H_ + h) * E_ + quad * 8;
    bf16x8 qf0 = load8_f2b(Q + qbase);
    bf16x8 qf1 = load8_f2b(Q + qbase + 32);

    const float scale = 0.125f;  // 1/sqrt(64)
    int nsb = lt + 1;            // 16-wide s-blocks needed (causal)
    int rg  = l0 + lm;           // this lane's global l-row
    const float* Arow = A + ((size_t)bh * L_ + l0 + lm) * S_;
    const ushort* VTrow = VT + ((size_t)bh * D_ + lm) * S_;  // d-row lm (dd adds 16*S_)

    auto load_frag = [&](int sb) {
        Frag f;
        int s0 = sb << 4;
        int c0 = s0 + quad * 4;
        const size_t kbase = ((size_t)(b * S_ + s0 + lm) * H_ + h) * E_ + quad * 8;
        if (USE_WS) {
            f.kf0 = *(const bf16x8*)(KB + kbase);
            f.kf1 = *(const bf16x8*)(KB + kbase + 32);
        } else {
            f.kf0 = load8_f2b(K + kbase);
            f.kf1 = load8_f2b(K + kbase + 32);
        }
        f.a4 = *(const float4*)(Arow + c0);
        if (USE_WS) {
            f.vr0 = *(const u16x4*)(VTrow + (size_t)0 * 16 * S_ + c0);
            f.vr1 = *(const u16x4*)(VTrow + (size_t)1 * 16 * S_ + c0);
            f.vr2 = *(const u16x4*)(VTrow + (size_t)2 * 16 * S_ + c0);
            f.vr3 = *(const u16x4*)(VTrow + (size_t)3 * 16 * S_ + c0);
        } else {
            u16x4 vr[4];
#pragma unroll
            for (int dd = 0; dd < 4; ++dd)
#pragma unroll
                for (int j = 0; j < 4; ++j)
                    vr[dd][j] = f2b(V[((size_t)(b * S_ + c0 + j) * H_ + h) * D_ + dd * 16 + lm]);
            f.vr0 = vr[0]; f.vr1 = vr[1]; f.vr2 = vr[2]; f.vr3 = vr[3];
        }
        return f;
    };

    // --- main loop: depth-2 pipelined; scores -> exp -> stash(bf16) + reg PV ---
    float psum = 0.f;
    u16x4 stash[16];              // statically indexed (full unroll)
    f32x4 oacc[4] = {{0.f,0.f,0.f,0.f},{0.f,0.f,0.f,0.f},{0.f,0.f,0.f,0.f},{0.f,0.f,0.f,0.f}};
    Frag cur, nxt;
    if (wave < nsb) cur = load_frag(wave);
#pragma unroll
    for (int i = 0; i < 16; ++i) {
        int sb  = wave + i * 4;   // wave w owns s-blocks w, w+4, ...
        int sbn = sb + 4;
        if (sbn < nsb) nxt = load_frag(sbn);  // prefetch next iteration's operands
        if (sb < nsb) {
            int c0 = (sb << 4) + quad * 4;
            f32x4 acc = {0.f, 0.f, 0.f, 0.f};
            acc = __builtin_amdgcn_mfma_f32_16x16x32_bf16(cur.kf0, qf0, acc, 0, 0, 0);
            acc = __builtin_amdgcn_mfma_f32_16x16x32_bf16(cur.kf1, qf1, acc, 0, 0, 0);
            u16x4 ps;
            bf16x4 pf;
#pragma unroll
            for (int r = 0; r < 4; ++r) {
                float av = (r == 0) ? cur.a4.x : (r == 1) ? cur.a4.y : (r == 2) ? cur.a4.z : cur.a4.w;
                float z = acc[r] * scale + av;
                float p = (c0 + r <= rg) ? __expf(z) : 0.f;  // mask (incl. diagonal block)
                psum += p;
                ps[r] = f2b(p);
                pf[r] = (short)ps[r];
            }
            stash[i] = ps;
            // PV: O[l=quad*4+r][d=dd*16+lm] += P[lm-row][c0+j] * V[c0+j][d]
            bf16x4 v0, v1, v2, v3;
#pragma unroll
            for (int j = 0; j < 4; ++j) {
                v0[j] = (short)cur.vr0[j]; v1[j] = (short)cur.vr1[j];
                v2[j] = (short)cur.vr2[j]; v3[j] = (short)cur.vr3[j];
            }
            oacc[0] = mfma16(pf, v0, oacc[0]);
            oacc[1] = mfma16(pf, v1, oacc[1]);
            oacc[2] = mfma16(pf, v2, oacc[2]);
            oacc[3] = mfma16(pf, v3, oacc[3]);
        }
        cur = nxt;
    }

    // --- row-sum reduce across quads, publish per-wave sums + partial O ---
    psum += __shfl_xor(psum, 16);
    psum += __shfl_xor(psum, 32);
    if (quad == 0) red[wave][lm] = psum;
#pragma unroll
    for (int dd = 0; dd < 4; ++dd)
#pragma unroll
        for (int r = 0; r < 4; ++r)
            obuf[wave][quad * 4 + r][dd * 16 + lm] = oacc[dd][r];
    __syncthreads();

    // --- outV: cross-wave O reduction + normalize (256B/row coalesced) ---
#pragma unroll
    for (int i = 0; i < 4; ++i) {
        int slot = t + i * 256;
        int l = slot >> 6, d = slot & 63;
        float sum = obuf[0][l][d] + obuf[1][l][d] + obuf[2][l][d] + obuf[3][l][d];
        float inv = 1.0f / (red[0][l] + red[1][l] + red[2][l] + red[3][l]);
        outV[((size_t)(b * L_ + l0 + l) * H_ + h) * D_ + d] = sum * inv;
    }

    // --- outA: 4 chunks of 256 cols; stash -> LDS (scatter) -> coalesced 1KB stores ---
    float invA[4];
#pragma unroll
    for (int r = 0; r < 4; ++r) {
        int R = wave * 4 + r;
        invA[r] = 1.0f / (red[0][R] + red[1][R] + red[2][R] + red[3][R]);
    }
    ushort* cb = (ushort*)&obuf[0][0][0];  // [16][264] bf16 stage (8448B <= obuf)
#pragma unroll
    for (int c = 0; c < 4; ++c) {
        __syncthreads();  // c==0: obuf reads done; c>0: previous cb reads done
#pragma unroll
        for (int j = 0; j < 4; ++j) {
            int i  = c * 4 + j;
            int sb = wave + i * 4;        // = wave + 16c + 4j
            int lb = wave + 4 * j;        // local 16-block within chunk
            u16x4 ps = {0, 0, 0, 0};
            if (sb < nsb) ps = stash[i];  // beyond-diagonal blocks -> zeros
            *(u16x4*)&cb[lm * 264 + lb * 16 + quad * 4] = ps;
        }
        __syncthreads();
#pragma unroll
        for (int r = 0; r < 4; ++r) {
            int R = wave * 4 + r;
            u16x4 pv = *(const u16x4*)&cb[R * 264 + lane * 4];
            float4 o;
            o.x = b2f(pv[0]) * invA[r];
            o.y = b2f(pv[1]) * invA[r];
            o.z = b2f(pv[2]) * invA[r];
            o.w = b2f(pv[3]) * invA[r];
            *(float4*)(outA + ((size_t)bh * L_ + l0 + R) * S_ + c * 256 + lane * 4) = o;
        }
    }
}

extern "C" void kernel_launch(void* const* d_in, const int* in_sizes, int n_in,
                              void* d_out, int out_size, void* d_ws, size_t ws_size,
                              hipStream_t stream) {
    const float* Q = (const float*)d_in[0];
    const float* K = (const float*)d_in[1];
    const float* V = (const float*)d_in[2];
    // d_in[3] = attn_mask (bool): causal strict-upper-tri, synthesized in-kernel
    const float* A = (const float*)d_in[4];
    float* outV = (float*)d_out;                        // fp32 out: V (B,L,H,D)
    float* outA = outV + (size_t)B_ * L_ * H_ * D_;     // then A_new (B,H,L,S)

    size_t vt_elems = (size_t)B_ * H_ * D_ * S_;
    size_t kb_elems = (size_t)B_ * S_ * H_ * E_;
    size_t need = (vt_elems + kb_elems) * sizeof(ushort);
    ushort* VT = (ushort*)d_ws;
    ushort* KB = VT + vt_elems;

    if (ws_size >= need) {
        vt_kernel<<<B_ * H_ * (S_ / 64), 256, 0, stream>>>(V, VT);
        kb_kernel<<<(int)(kb_elems / (256 * 8)), 256, 0, stream>>>(K, KB);
        attn_kernel<1><<<B_ * H_ * (L_ / 16), 256, 0, stream>>>(Q, K, A, KB, VT, V, outV, outA);
    } else {
        attn_kernel<0><<<B_ * H_ * (L_ / 16), 256, 0, stream>>>(Q, K, A, KB, VT, V, outV, outA);
    }
}